// Round 8
// baseline (192.129 us; speedup 1.0000x reference)
//
#include <hip/hip_runtime.h>
#include <math.h>

#define F 128   // F_IN == F_HID == F_OUT == 128
#define N_GRAPHS 256
#define BK_SHIFT 8                // 256 nodes per bucket
#define BK_NODES 256
#define BK_CAP 6144               // padded per-bucket capacity
#define MAXBK 512                 // LDS histogram capacity (nBk = 391)
#define SC_CAP 3200               // scatter LDS edge-chunk capacity
#define NSCAT 512                 // scatter blocks in fused kernel

typedef __attribute__((ext_vector_type(4))) float f32x4;
typedef __attribute__((ext_vector_type(2))) float f32x2;
typedef __attribute__((ext_vector_type(8))) short bf16x8;
typedef __attribute__((ext_vector_type(8))) unsigned short u16x8;

// ---- bf16 helpers -----------------------------------------------------------
__device__ __forceinline__ unsigned short f2bf(float f) {
    unsigned u = __float_as_uint(f);
    unsigned r = (u + 0x7FFFu + ((u >> 16) & 1u)) >> 16;  // RNE
    return (unsigned short)r;
}
__device__ __forceinline__ float bf2f(unsigned short u) {
    return __uint_as_float(((unsigned)u) << 16);
}
// dtype-aware index read: int64 inputs have zero high words (values < 2^31)
__device__ __forceinline__ int idxval(const int* raw, int i, bool is32) {
    return is32 ? raw[i] : (int)((const long long*)raw)[i];
}

// ---- fp8 e4m3 helpers (hw converts w/ software fallback) ---------------------
#if defined(__has_builtin)
#if __has_builtin(__builtin_amdgcn_cvt_pk_f32_fp8) && __has_builtin(__builtin_amdgcn_cvt_pk_fp8_f32)
#define HW_FP8 1
#endif
#endif

__device__ __forceinline__ unsigned char f2fp8(float f) {
#ifdef HW_FP8
    int p = __builtin_amdgcn_cvt_pk_fp8_f32(f, f, 0, false);
    return (unsigned char)(p & 0xFF);
#else
    float a = fabsf(f);
    unsigned s = (f < 0.f) ? 0x80u : 0u;
    if (a >= 448.f) return s | 0x7E;
    if (a < 0.015625f) {                  // subnormal: m * 2^-9
        int m = (int)(a * 512.f + 0.5f);  // <= 8; 8 encodes as exp=1,m=0
        return s | (unsigned)m;
    }
    int ex;
    float fr = frexpf(a, &ex);            // a = fr*2^ex, fr in [0.5,1)
    int e = ex - 1;                       // floor(log2 a)
    int q = (int)(a * exp2f((float)(3 - e)) + 0.5f) - 8;  // mantissa 0..8
    if (q == 8) { q = 0; e += 1; }
    return s | ((unsigned)(e + 7) << 3) | (unsigned)q;
#endif
}

__device__ __forceinline__ void fp8x8_add(uint2 v, float* acc) {
#ifdef HW_FP8
    f32x2 p;
    p = __builtin_amdgcn_cvt_pk_f32_fp8((int)v.x, false); acc[0] += p[0]; acc[1] += p[1];
    p = __builtin_amdgcn_cvt_pk_f32_fp8((int)v.x, true);  acc[2] += p[0]; acc[3] += p[1];
    p = __builtin_amdgcn_cvt_pk_f32_fp8((int)v.y, false); acc[4] += p[0]; acc[5] += p[1];
    p = __builtin_amdgcn_cvt_pk_f32_fp8((int)v.y, true);  acc[6] += p[0]; acc[7] += p[1];
#else
    unsigned w[2] = {v.x, v.y};
#pragma unroll
    for (int j = 0; j < 8; ++j) {
        unsigned b = (w[j >> 2] >> ((j & 3) * 8)) & 0xFF;
        int e = (b >> 3) & 0xF, m = b & 7;
        float val = e ? ldexpf((float)(8 + m), e - 10) : ldexpf((float)m, -9);
        acc[j] += (b & 0x80) ? -val : val;
    }
#endif
}

// ---------------------------------------------------------------------------
// K1: in-degree counts (global atomics on 400KB) + W1T bf16 transpose side-job.
// ---------------------------------------------------------------------------
__global__ __launch_bounds__(256) void count_w1t_kernel(
    const int* __restrict__ ei_raw, int nE,
    const int* __restrict__ batch_raw, int nN,
    const float* __restrict__ W1, unsigned short* __restrict__ W1T,
    int* __restrict__ cnt) {
    int t = threadIdx.x;
    if (blockIdx.x < 64) {
        int i = blockIdx.x * 256 + t;     // 16384 elems
        int k = i >> 7, n = i & 127;
        W1T[n * F + k] = f2bf(W1[i]);
    }
    bool is32 = (batch_raw[nN - 1] != 0);
    int e = blockIdx.x * 256 + t;
    if (e >= nE) return;
    int c = idxval(ei_raw, nE + e, is32);
    atomicAdd(&cnt[c], 1);
}

// ---------------------------------------------------------------------------
// K2: FUSED scatter || gemm. Blocks [0,NSCAT): reservation bucket-scatter of
// edges into tmp. Blocks [NSCAT,...): h' = dinv * (x @ W1) MFMA tiles (fp8 out).
// Independent work -> runs concurrently; 32KB dynamic LDS aliased per path.
// ---------------------------------------------------------------------------
__global__ __launch_bounds__(256) void scatter_gemm_kernel(
    const int* __restrict__ ei_raw, int nE,
    const int* __restrict__ batch_raw, int nN,
    const float* __restrict__ x, const unsigned short* __restrict__ W1T,
    const int* __restrict__ cnt, unsigned char* __restrict__ h_f8,
    int* __restrict__ bcursor, int2* __restrict__ tmp, int nBk) {
    extern __shared__ char smem[];
    int t = threadIdx.x;

    if (blockIdx.x < NSCAT) {
        // ---------------- scatter path ----------------
        int2* ebuf  = (int2*)smem;                       // SC_CAP*8 = 25.6KB
        int*  hist  = (int*)(smem + SC_CAP * 8);         // 2KB
        int*  rbase = hist + MAXBK;                      // 2KB
        bool is32 = (batch_raw[nN - 1] != 0);
        int cs = (nE + NSCAT - 1) / NSCAT;               // 3125 <= SC_CAP
        int e0 = blockIdx.x * cs;
        int e1 = min(nE, e0 + cs);

        for (int s0 = e0; s0 < e1; s0 += SC_CAP) {
            int m = min(SC_CAP, e1 - s0);
            for (int i = t; i < nBk; i += 256) hist[i] = 0;
            __syncthreads();
            for (int i = t; i < m; i += 256) {
                int r = idxval(ei_raw, s0 + i, is32);
                int c = idxval(ei_raw, nE + s0 + i, is32);
                ebuf[i] = make_int2(r, c);
                atomicAdd(&hist[c >> BK_SHIFT], 1);
            }
            __syncthreads();
            for (int i = t; i < nBk; i += 256) {
                int hv = hist[i];
                rbase[i] = hv ? (i * BK_CAP + atomicAdd(&bcursor[i], hv)) : 0;
                hist[i] = 0;
            }
            __syncthreads();
            for (int i = t; i < m; i += 256) {
                int2 e = ebuf[i];
                int b = e.y >> BK_SHIFT;
                int pos = rbase[b] + atomicAdd(&hist[b], 1);
                if (pos < (b + 1) * BK_CAP)  // capacity guard
                    tmp[pos] = e;
            }
            __syncthreads();
        }
    } else {
        // ---------------- gemm path ----------------
        unsigned short* xs = (unsigned short*)smem;      // 128*128 bf16 = 32KB
        int row0 = (blockIdx.x - NSCAT) * 128;

#pragma unroll
        for (int j = 0; j < 16; ++j) {
            int idx = t + j * 256;        // float4 index within [128][32]
            int r = idx >> 5, c4 = idx & 31;
            int gr = row0 + r;
            float4 v = make_float4(0.f, 0.f, 0.f, 0.f);
            if (gr < nN) v = ((const float4*)x)[(size_t)gr * 32 + c4];
            ushort4 o;
            o.x = f2bf(v.x); o.y = f2bf(v.y); o.z = f2bf(v.z); o.w = f2bf(v.w);
            int byte = (r * 256 + c4 * 8) ^ ((r & 7) << 4);
            *(ushort4*)((char*)xs + byte) = o;
        }
        __syncthreads();

        int lane = t & 63;
        int w = t >> 6;              // wave 0..3
        int m0 = (w >> 1) * 64;
        int n0 = (w & 1) * 64;
        int l15 = lane & 15;
        int lg = lane >> 4;

        f32x4 acc[4][4] = {};
#pragma unroll
        for (int ks = 0; ks < 4; ++ks) {
            bf16x8 a[4], b[4];
#pragma unroll
            for (int i = 0; i < 4; ++i) {
                int r = m0 + i * 16 + l15;
                int byte = (r * 256 + ks * 64 + lg * 16) ^ ((r & 7) << 4);
                a[i] = *(const bf16x8*)((const char*)xs + byte);
            }
#pragma unroll
            for (int j = 0; j < 4; ++j) {
                int n = n0 + j * 16 + l15;
                b[j] = *(const bf16x8*)(W1T + (size_t)n * F + ks * 32 + lg * 8);
            }
#pragma unroll
            for (int i = 0; i < 4; ++i)
#pragma unroll
                for (int j = 0; j < 4; ++j)
                    acc[i][j] = __builtin_amdgcn_mfma_f32_16x16x32_bf16(
                        a[i], b[j], acc[i][j], 0, 0, 0);
        }

        // epilogue: h' = dinv(row) * acc, store fp8 bytes
#pragma unroll
        for (int i = 0; i < 4; ++i) {
#pragma unroll
            for (int r = 0; r < 4; ++r) {
                int gm = row0 + m0 + i * 16 + lg * 4 + r;
                if (gm < nN) {
                    float dv = rsqrtf((float)(cnt[gm] + 1));
#pragma unroll
                    for (int j = 0; j < 4; ++j) {
                        int n = n0 + j * 16 + l15;
                        h_f8[(size_t)gm * F + n] = f2fp8(dv * acc[i][j][r]);
                    }
                }
            }
        }
    }
}

// ---------------------------------------------------------------------------
// K3: fused per-bucket histogram + emit (src-only CSR, 4-aligned offsets).
// ---------------------------------------------------------------------------
__global__ __launch_bounds__(256) void bucket_build_kernel(
    const int2* __restrict__ tmp, const int* __restrict__ bfill, int nN,
    int* __restrict__ off, int* __restrict__ csr) {
    __shared__ int h[BK_NODES];
    __shared__ int pfx[BK_NODES];
    __shared__ int lcur[BK_NODES];
    int b = blockIdx.x;
    int t = threadIdx.x;
    int nodeLo = b << BK_SHIFT;
    int base = b * BK_CAP;
    int m = min(bfill[b], BK_CAP);

    h[t] = 0;
    __syncthreads();
    for (int i = t; i < m; i += 256)
        atomicAdd(&h[tmp[base + i].y - nodeLo], 1);
    __syncthreads();
    int own = h[t];
    int pad = (own + 3) & ~3;       // 4-align each node's list
    pfx[t] = pad;
    __syncthreads();
    for (int st = 1; st < 256; st <<= 1) {
        int add = (t >= st) ? pfx[t - st] : 0;
        __syncthreads();
        pfx[t] += add;
        __syncthreads();
    }
    int myoff = base + pfx[t] - pad;
    lcur[t] = myoff;
    int node = nodeLo + t;
    if (node < nN) off[node] = myoff;
    __syncthreads();
    for (int i = t; i < m; i += 256) {
        int2 e = tmp[base + i];
        int pos = atomicAdd(&lcur[e.y - nodeLo], 1);
        csr[pos] = e.x;
    }
}

// ---------------------------------------------------------------------------
// K4: gather-aggregate, fp8 rows:
//   agg[c] = relu(b1 + dinv[c] * (h'[c] + sum_e h'[src_e]))
// 16 lanes x 8B (uint2 = 8 fp8) per row, 16 nodes / 256-thr block.
// ---------------------------------------------------------------------------
__global__ __launch_bounds__(256) void aggregate_kernel(
    const unsigned char* __restrict__ h_f8, const int* __restrict__ csr,
    const int* __restrict__ off, const int* __restrict__ cnt,
    const float* __restrict__ b1, unsigned short* __restrict__ agg_bf,
    int nN) {
    int t = threadIdx.x;
    int lane = t & 15;                 // features lane*8 .. lane*8+7
    int c = blockIdx.x * 16 + (t >> 4);
    if (c >= nN) return;

    const uint2* h2 = (const uint2*)h_f8;   // 16 x 8B per row
    float acc[8];
#pragma unroll
    for (int j = 0; j < 8; ++j) acc[j] = 0.f;
    fp8x8_add(h2[(size_t)c * 16 + lane], acc);   // self term

    int lo = off[c];                   // 4-aligned
    int n = cnt[c];
    int k = 0;
    for (; k + 4 <= n; k += 4) {
        int4 e = *(const int4*)(csr + lo + k);
        uint2 v0 = h2[(size_t)e.x * 16 + lane];
        uint2 v1 = h2[(size_t)e.y * 16 + lane];
        uint2 v2 = h2[(size_t)e.z * 16 + lane];
        uint2 v3 = h2[(size_t)e.w * 16 + lane];
        fp8x8_add(v0, acc);
        fp8x8_add(v1, acc);
        fp8x8_add(v2, acc);
        fp8x8_add(v3, acc);
    }
    if (k < n) {
        int4 e = *(const int4*)(csr + lo + k);   // aligned; pad slots guarded
        fp8x8_add(h2[(size_t)e.x * 16 + lane], acc);
        if (k + 1 < n) fp8x8_add(h2[(size_t)e.y * 16 + lane], acc);
        if (k + 2 < n) fp8x8_add(h2[(size_t)e.z * 16 + lane], acc);
    }

    float dc = rsqrtf((float)(n + 1));
    const float* b1p = b1 + lane * 8;
    u16x8 r;
#pragma unroll
    for (int j = 0; j < 8; ++j) {
        float v = b1p[j] + dc * acc[j];
        r[j] = f2bf(fmaxf(v, 0.f));
    }
    *(u16x8*)(agg_bf + (size_t)c * F + lane * 8) = r;
}

// ---------------------------------------------------------------------------
// K5: fused global-mean-pool + linear + tanh. One block per graph, 256 thr.
// ---------------------------------------------------------------------------
__global__ __launch_bounds__(256) void pool_final_kernel(
    const unsigned short* __restrict__ agg_bf,
    const int* __restrict__ batch_raw, int nN,
    const float* __restrict__ W2, const float* __restrict__ b2,
    float* __restrict__ out) {
    int g = blockIdx.x;
    bool is32 = (batch_raw[nN - 1] != 0);
    __shared__ int bounds[2];
    __shared__ float sd[16][F];
    __shared__ float ps[F];
    int t = threadIdx.x;
    if (t < 2) {
        int target = g + t;
        int lo = 0, hi = nN;
        while (lo < hi) {
            int mid = (lo + hi) >> 1;
            if (idxval(batch_raw, mid, is32) < target) lo = mid + 1; else hi = mid;
        }
        bounds[t] = lo;
    }
    __syncthreads();
    int lo = bounds[0], hi = bounds[1];

    int lane = t & 15;
    int grp = t >> 4;
    const u16x8* a8 = (const u16x8*)agg_bf;
    float acc[8];
#pragma unroll
    for (int j = 0; j < 8; ++j) acc[j] = 0.f;
    for (int n = lo + grp; n < hi; n += 16) {
        u16x8 v = a8[(size_t)n * 16 + lane];
#pragma unroll
        for (int j = 0; j < 8; ++j) acc[j] += bf2f(v[j]);
    }
#pragma unroll
    for (int j = 0; j < 8; ++j) sd[grp][lane * 8 + j] = acc[j];
    __syncthreads();

    if (t < F) {
        float s = 0.f;
#pragma unroll
        for (int i = 0; i < 16; ++i) s += sd[i][t];
        float cntf = (float)(hi - lo);
        ps[t] = s / fmaxf(cntf, 1.0f);
    }
    __syncthreads();

    if (t < F) {
        float s = b2[t];
        for (int k = 0; k < F; ++k) s += ps[k] * W2[k * F + t];
        out[g * F + t] = tanhf(s);
    }
}

// ---------------------------------------------------------------------------
extern "C" void kernel_launch(void* const* d_in, const int* in_sizes, int n_in,
                              void* d_out, int out_size, void* d_ws, size_t ws_size,
                              hipStream_t stream) {
    const float* x     = (const float*)d_in[0];
    const int*   ei    = (const int*)d_in[1];
    const int*   batch = (const int*)d_in[2];
    const float* W1    = (const float*)d_in[3];
    const float* b1    = (const float*)d_in[4];
    const float* W2    = (const float*)d_in[5];
    const float* b2    = (const float*)d_in[6];
    float* out = (float*)d_out;

    const int nN = in_sizes[2];                       // 100000
    const int nE = in_sizes[1] / 2;                   // 1600000
    const int nBk = (nN + BK_NODES - 1) >> BK_SHIFT;  // 391 buckets
    const int nGemm = (nN + 127) / 128;               // 782

    char* ws = (char*)d_ws;
    size_t woff = 0;
    auto take = [&](size_t bytes) {
        void* p = ws + woff;
        woff += (bytes + 15) & ~(size_t)15;
        return p;
    };
    unsigned char*  h_f8   = (unsigned char*)take((size_t)nN * F);
    unsigned short* agg_bf = (unsigned short*)take((size_t)nN * F * 2);
    int2*  tmp      = (int2*)take((size_t)nBk * BK_CAP * 8);
    int*   csr      = (int*)take((size_t)nBk * BK_CAP * 4);
    int*   cnt      = (int*)take((size_t)(nN + nBk) * 4);  // cnt + bcursor adjacent
    int*   bcursor  = cnt + nN;
    int*   off      = (int*)take((size_t)nN * 4);
    unsigned short* W1T = (unsigned short*)take((size_t)F * F * 2);

    hipMemsetAsync(cnt, 0, (size_t)(nN + nBk) * 4, stream);
    count_w1t_kernel<<<(nE + 255) / 256, 256, 0, stream>>>(ei, nE, batch, nN,
                                                           W1, W1T, cnt);
    scatter_gemm_kernel<<<NSCAT + nGemm, 256, 32768, stream>>>(
        ei, nE, batch, nN, x, W1T, cnt, h_f8, bcursor, tmp, nBk);
    bucket_build_kernel<<<nBk, 256, 0, stream>>>(tmp, bcursor, nN, off, csr);
    aggregate_kernel<<<(nN + 15) / 16, 256, 0, stream>>>(h_f8, csr, off, cnt,
                                                         b1, agg_bf, nN);
    pool_final_kernel<<<N_GRAPHS, 256, 0, stream>>>(agg_bf, batch, nN, W2, b2, out);
}

// Round 9
// 130.291 us; speedup vs baseline: 1.4746x; 1.4746x over previous
//
#include <hip/hip_runtime.h>
#include <math.h>

#define F 128   // F_IN == F_HID == F_OUT == 128
#define N_GRAPHS 256
#define BK_SHIFT 8                // 256 nodes per bucket
#define BK_NODES 256
#define BK_CAP 6144               // padded per-bucket capacity (mean ~4092, +32 sigma)
#define MAXBK 512                 // LDS bucket-histogram capacity (nBk = 391)
#define SC_CAP 3200               // scatter LDS edge-chunk capacity
#define NSCAT 512                 // scatter blocks in fused kernel A

typedef __attribute__((ext_vector_type(4))) float f32x4;
typedef __attribute__((ext_vector_type(2))) float f32x2;
typedef __attribute__((ext_vector_type(8))) short bf16x8;
typedef __attribute__((ext_vector_type(8))) unsigned short u16x8;

// ---- bf16 helpers -----------------------------------------------------------
__device__ __forceinline__ unsigned short f2bf(float f) {
    unsigned u = __float_as_uint(f);
    unsigned r = (u + 0x7FFFu + ((u >> 16) & 1u)) >> 16;  // RNE
    return (unsigned short)r;
}
__device__ __forceinline__ float bf2f(unsigned short u) {
    return __uint_as_float(((unsigned)u) << 16);
}
// dtype-aware index read: int64 inputs have zero high words (values < 2^31)
__device__ __forceinline__ int idxval(const int* raw, int i, bool is32) {
    return is32 ? raw[i] : (int)((const long long*)raw)[i];
}

// ---- fp8 e4m3 helpers (hw converts w/ software fallback; self-consistent) ----
#if defined(__has_builtin)
#if __has_builtin(__builtin_amdgcn_cvt_pk_f32_fp8) && __has_builtin(__builtin_amdgcn_cvt_pk_fp8_f32)
#define HW_FP8 1
#endif
#endif

__device__ __forceinline__ unsigned char f2fp8(float f) {
#ifdef HW_FP8
    int p = __builtin_amdgcn_cvt_pk_fp8_f32(f, f, 0, false);
    return (unsigned char)(p & 0xFF);
#else
    float a = fabsf(f);
    unsigned s = (f < 0.f) ? 0x80u : 0u;
    if (a >= 448.f) return s | 0x7E;
    if (a < 0.015625f) {
        int m = (int)(a * 512.f + 0.5f);
        return s | (unsigned)m;
    }
    int ex;
    float fr = frexpf(a, &ex);
    int e = ex - 1;
    int q = (int)(a * exp2f((float)(3 - e)) + 0.5f) - 8;
    if (q == 8) { q = 0; e += 1; }
    return s | ((unsigned)(e + 7) << 3) | (unsigned)q;
#endif
}

// 16 fp8 (uint4) fused multiply-add into acc[16] with scalar weight w
__device__ __forceinline__ void fp8x16_fma(uint4 v, float w, float* acc) {
#ifdef HW_FP8
    f32x2 p;
    p = __builtin_amdgcn_cvt_pk_f32_fp8((int)v.x, false); acc[0]  += w * p[0]; acc[1]  += w * p[1];
    p = __builtin_amdgcn_cvt_pk_f32_fp8((int)v.x, true);  acc[2]  += w * p[0]; acc[3]  += w * p[1];
    p = __builtin_amdgcn_cvt_pk_f32_fp8((int)v.y, false); acc[4]  += w * p[0]; acc[5]  += w * p[1];
    p = __builtin_amdgcn_cvt_pk_f32_fp8((int)v.y, true);  acc[6]  += w * p[0]; acc[7]  += w * p[1];
    p = __builtin_amdgcn_cvt_pk_f32_fp8((int)v.z, false); acc[8]  += w * p[0]; acc[9]  += w * p[1];
    p = __builtin_amdgcn_cvt_pk_f32_fp8((int)v.z, true);  acc[10] += w * p[0]; acc[11] += w * p[1];
    p = __builtin_amdgcn_cvt_pk_f32_fp8((int)v.w, false); acc[12] += w * p[0]; acc[13] += w * p[1];
    p = __builtin_amdgcn_cvt_pk_f32_fp8((int)v.w, true);  acc[14] += w * p[0]; acc[15] += w * p[1];
#else
    unsigned ww[4] = {v.x, v.y, v.z, v.w};
#pragma unroll
    for (int j = 0; j < 16; ++j) {
        unsigned b = (ww[j >> 2] >> ((j & 3) * 8)) & 0xFF;
        int e = (b >> 3) & 0xF, m = b & 7;
        float val = e ? ldexpf((float)(8 + m), e - 10) : ldexpf((float)m, -9);
        acc[j] += (b & 0x80) ? -(w * val) : (w * val);
    }
#endif
}

// ---------------------------------------------------------------------------
// Kernel A: FUSED scatter || gemm (independent work, 64KB dynamic LDS aliased).
// Blocks [0,NSCAT): reservation bucket-scatter of raw edges into tmp.
// Blocks [NSCAT,..): h = x @ W1 MFMA tiles, UNSCALED fp8 out; each block
// converts W1 -> swizzled bf16 LDS itself (W1 is L2-resident).
// ---------------------------------------------------------------------------
__global__ __launch_bounds__(256) void scatter_gemm_kernel(
    const int* __restrict__ ei_raw, int nE,
    const int* __restrict__ batch_raw, int nN,
    const float* __restrict__ x, const float* __restrict__ W1,
    unsigned char* __restrict__ h_f8,
    int* __restrict__ bcursor, int2* __restrict__ tmp, int nBk) {
    extern __shared__ char smem[];
    int t = threadIdx.x;

    if (blockIdx.x < NSCAT) {
        // ---------------- scatter path ----------------
        int2* ebuf  = (int2*)smem;                       // SC_CAP*8 = 25.6KB
        int*  hist  = (int*)(smem + SC_CAP * 8);         // 2KB
        int*  rbase = hist + MAXBK;                      // 2KB
        bool is32 = (batch_raw[nN - 1] != 0);
        int cs = (nE + NSCAT - 1) / NSCAT;               // 3125 <= SC_CAP
        int e0 = blockIdx.x * cs;
        int e1 = min(nE, e0 + cs);

        for (int s0 = e0; s0 < e1; s0 += SC_CAP) {
            int m = min(SC_CAP, e1 - s0);
            for (int i = t; i < nBk; i += 256) hist[i] = 0;
            __syncthreads();
            for (int i = t; i < m; i += 256) {
                int r = idxval(ei_raw, s0 + i, is32);
                int c = idxval(ei_raw, nE + s0 + i, is32);
                ebuf[i] = make_int2(r, c);
                atomicAdd(&hist[c >> BK_SHIFT], 1);
            }
            __syncthreads();
            for (int i = t; i < nBk; i += 256) {
                int hv = hist[i];
                rbase[i] = hv ? (i * BK_CAP + atomicAdd(&bcursor[i], hv)) : 0;
                hist[i] = 0;
            }
            __syncthreads();
            for (int i = t; i < m; i += 256) {
                int2 e = ebuf[i];
                int b = e.y >> BK_SHIFT;
                int pos = rbase[b] + atomicAdd(&hist[b], 1);
                if (pos < (b + 1) * BK_CAP)  // capacity guard
                    tmp[pos] = e;
            }
            __syncthreads();
        }
    } else {
        // ---------------- gemm path ----------------
        unsigned short* xs = (unsigned short*)smem;             // 32KB swizzled x
        unsigned short* wl = (unsigned short*)(smem + 32768);   // 32KB swizzled W1T
        int row0 = (blockIdx.x - NSCAT) * 128;

        // stage W1 -> transposed swizzled bf16 LDS: wl[n][k]
        for (int cch = t; cch < 2048; cch += 256) {   // 16B chunks: 128n x 16kc
            int n = cch & 127, kc = cch >> 7;
            u16x8 o;
#pragma unroll
            for (int j = 0; j < 8; ++j) o[j] = f2bf(W1[(kc * 8 + j) * F + n]);
            int byte = (n * 256 + kc * 16) ^ ((n & 7) << 4);
            *(u16x8*)((char*)wl + byte) = o;
        }
        // stage x tile -> swizzled bf16 LDS
#pragma unroll
        for (int j = 0; j < 16; ++j) {
            int idx = t + j * 256;        // float4 index within [128][32]
            int r = idx >> 5, c4 = idx & 31;
            int gr = row0 + r;
            float4 v = make_float4(0.f, 0.f, 0.f, 0.f);
            if (gr < nN) v = ((const float4*)x)[(size_t)gr * 32 + c4];
            ushort4 o;
            o.x = f2bf(v.x); o.y = f2bf(v.y); o.z = f2bf(v.z); o.w = f2bf(v.w);
            int byte = (r * 256 + c4 * 8) ^ ((r & 7) << 4);
            *(ushort4*)((char*)xs + byte) = o;
        }
        __syncthreads();

        int lane = t & 63;
        int w = t >> 6;              // wave 0..3
        int m0 = (w >> 1) * 64;
        int n0 = (w & 1) * 64;
        int l15 = lane & 15;
        int lg = lane >> 4;

        f32x4 acc[4][4] = {};
#pragma unroll
        for (int ks = 0; ks < 4; ++ks) {
            bf16x8 a[4], b[4];
#pragma unroll
            for (int i = 0; i < 4; ++i) {
                int r = m0 + i * 16 + l15;
                int byte = (r * 256 + ks * 64 + lg * 16) ^ ((r & 7) << 4);
                a[i] = *(const bf16x8*)((const char*)xs + byte);
            }
#pragma unroll
            for (int j = 0; j < 4; ++j) {
                int n = n0 + j * 16 + l15;
                int byte = (n * 256 + ks * 64 + lg * 16) ^ ((n & 7) << 4);
                b[j] = *(const bf16x8*)((const char*)wl + byte);
            }
#pragma unroll
            for (int i = 0; i < 4; ++i)
#pragma unroll
                for (int j = 0; j < 4; ++j)
                    acc[i][j] = __builtin_amdgcn_mfma_f32_16x16x32_bf16(
                        a[i], b[j], acc[i][j], 0, 0, 0);
        }

        // epilogue: store UNSCALED fp8
#pragma unroll
        for (int i = 0; i < 4; ++i) {
#pragma unroll
            for (int r = 0; r < 4; ++r) {
                int gm = row0 + m0 + i * 16 + lg * 4 + r;
                if (gm < nN) {
#pragma unroll
                    for (int j = 0; j < 4; ++j) {
                        int n = n0 + j * 16 + l15;
                        h_f8[(size_t)gm * F + n] = f2fp8(acc[i][j][r]);
                    }
                }
            }
        }
    }
}

// ---------------------------------------------------------------------------
// Kernel B: per-bucket build (single global pass; tmp chunk staged in LDS):
// cnt, dinv, 4-aligned absolute offsets, src-only CSR. All atomics LDS-local.
// ---------------------------------------------------------------------------
__global__ __launch_bounds__(256) void bucket_build_kernel(
    const int2* __restrict__ tmp, const int* __restrict__ bfill, int nN,
    int* __restrict__ off, int* __restrict__ cnt, float* __restrict__ dinv,
    int* __restrict__ csr) {
    __shared__ int2 ebuf[BK_CAP];     // 48KB
    __shared__ int h[BK_NODES];
    __shared__ int pfx[BK_NODES];
    __shared__ int lcur[BK_NODES];
    int b = blockIdx.x;
    int t = threadIdx.x;
    int nodeLo = b << BK_SHIFT;
    int base = b * BK_CAP;
    int m = min(bfill[b], BK_CAP);

    h[t] = 0;
    for (int i = t; i < m; i += 256) ebuf[i] = tmp[base + i];
    __syncthreads();
    for (int i = t; i < m; i += 256)
        atomicAdd(&h[ebuf[i].y - nodeLo], 1);
    __syncthreads();
    int own = h[t];
    int pad = (own + 3) & ~3;       // 4-align each node's list
    pfx[t] = pad;
    __syncthreads();
    for (int st = 1; st < 256; st <<= 1) {
        int add = (t >= st) ? pfx[t - st] : 0;
        __syncthreads();
        pfx[t] += add;
        __syncthreads();
    }
    int myoff = base + pfx[t] - pad;
    lcur[t] = myoff;
    int node = nodeLo + t;
    if (node < nN) {
        off[node] = myoff;
        cnt[node] = own;
        dinv[node] = rsqrtf((float)(own + 1));  // +1 self-loop
    }
    __syncthreads();
    for (int i = t; i < m; i += 256) {
        int2 e = ebuf[i];
        int pos = atomicAdd(&lcur[e.y - nodeLo], 1);
        csr[pos] = e.x;
    }
}

// ---------------------------------------------------------------------------
// Kernel C: gather-aggregate, fp8 rows, per-src dinv gather:
//   agg[c] = relu(b1 + dinv[c] * (dinv[c]*h[c] + sum_e dinv[src]*h[src]))
// 8 lanes x uint4 (16 fp8) per row, 32 nodes / 256-thr block -> 8 miss
// streams per wave for MLP.
// ---------------------------------------------------------------------------
__global__ __launch_bounds__(256) void aggregate_kernel(
    const unsigned char* __restrict__ h_f8, const int* __restrict__ csr,
    const int* __restrict__ off, const int* __restrict__ cnt,
    const float* __restrict__ dinv, const float* __restrict__ b1,
    unsigned short* __restrict__ agg_bf, int nN) {
    int t = threadIdx.x;
    int lane = t & 7;                  // features lane*16 .. lane*16+15
    int c = blockIdx.x * 32 + (t >> 3);
    if (c >= nN) return;

    const uint4* h4 = (const uint4*)h_f8;   // 8 x 16B per row
    int n = cnt[c];
    float dc = rsqrtf((float)(n + 1));
    float acc[16];
#pragma unroll
    for (int j = 0; j < 16; ++j) acc[j] = 0.f;
    fp8x16_fma(h4[(size_t)c * 8 + lane], dc, acc);   // self term (dinv[c]*h[c])

    int lo = off[c];                   // 4-aligned
    int k = 0;
    for (; k + 4 <= n; k += 4) {
        int4 e = *(const int4*)(csr + lo + k);
        float w0 = dinv[e.x];
        float w1 = dinv[e.y];
        float w2 = dinv[e.z];
        float w3 = dinv[e.w];
        uint4 v0 = h4[(size_t)e.x * 8 + lane];
        uint4 v1 = h4[(size_t)e.y * 8 + lane];
        uint4 v2 = h4[(size_t)e.z * 8 + lane];
        uint4 v3 = h4[(size_t)e.w * 8 + lane];
        fp8x16_fma(v0, w0, acc);
        fp8x16_fma(v1, w1, acc);
        fp8x16_fma(v2, w2, acc);
        fp8x16_fma(v3, w3, acc);
    }
    if (k < n) {
        int4 e = *(const int4*)(csr + lo + k);   // aligned; pad slots guarded
        fp8x16_fma(h4[(size_t)e.x * 8 + lane], dinv[e.x], acc);
        if (k + 1 < n) fp8x16_fma(h4[(size_t)e.y * 8 + lane], dinv[e.y], acc);
        if (k + 2 < n) fp8x16_fma(h4[(size_t)e.z * 8 + lane], dinv[e.z], acc);
    }

    const float* b1p = b1 + lane * 16;
    u16x8 r0, r1;
#pragma unroll
    for (int j = 0; j < 8; ++j) {
        r0[j] = f2bf(fmaxf(b1p[j] + dc * acc[j], 0.f));
        r1[j] = f2bf(fmaxf(b1p[8 + j] + dc * acc[8 + j], 0.f));
    }
    *(u16x8*)(agg_bf + (size_t)c * F + lane * 16) = r0;
    *(u16x8*)(agg_bf + (size_t)c * F + lane * 16 + 8) = r1;
}

// ---------------------------------------------------------------------------
// Kernel D: fused global-mean-pool + linear + tanh. One block per graph.
// ---------------------------------------------------------------------------
__global__ __launch_bounds__(256) void pool_final_kernel(
    const unsigned short* __restrict__ agg_bf,
    const int* __restrict__ batch_raw, int nN,
    const float* __restrict__ W2, const float* __restrict__ b2,
    float* __restrict__ out) {
    int g = blockIdx.x;
    bool is32 = (batch_raw[nN - 1] != 0);
    __shared__ int bounds[2];
    __shared__ float sd[16][F];
    __shared__ float ps[F];
    int t = threadIdx.x;
    if (t < 2) {
        int target = g + t;
        int lo = 0, hi = nN;
        while (lo < hi) {
            int mid = (lo + hi) >> 1;
            if (idxval(batch_raw, mid, is32) < target) lo = mid + 1; else hi = mid;
        }
        bounds[t] = lo;
    }
    __syncthreads();
    int lo = bounds[0], hi = bounds[1];

    int lane = t & 15;
    int grp = t >> 4;
    const u16x8* a8 = (const u16x8*)agg_bf;
    float acc[8];
#pragma unroll
    for (int j = 0; j < 8; ++j) acc[j] = 0.f;
    for (int n = lo + grp; n < hi; n += 16) {
        u16x8 v = a8[(size_t)n * 16 + lane];
#pragma unroll
        for (int j = 0; j < 8; ++j) acc[j] += bf2f(v[j]);
    }
#pragma unroll
    for (int j = 0; j < 8; ++j) sd[grp][lane * 8 + j] = acc[j];
    __syncthreads();

    if (t < F) {
        float s = 0.f;
#pragma unroll
        for (int i = 0; i < 16; ++i) s += sd[i][t];
        float cntf = (float)(hi - lo);
        ps[t] = s / fmaxf(cntf, 1.0f);
    }
    __syncthreads();

    if (t < F) {
        float s = b2[t];
        for (int k = 0; k < F; ++k) s += ps[k] * W2[k * F + t];
        out[g * F + t] = tanhf(s);
    }
}

// ---------------------------------------------------------------------------
extern "C" void kernel_launch(void* const* d_in, const int* in_sizes, int n_in,
                              void* d_out, int out_size, void* d_ws, size_t ws_size,
                              hipStream_t stream) {
    const float* x     = (const float*)d_in[0];
    const int*   ei    = (const int*)d_in[1];
    const int*   batch = (const int*)d_in[2];
    const float* W1    = (const float*)d_in[3];
    const float* b1    = (const float*)d_in[4];
    const float* W2    = (const float*)d_in[5];
    const float* b2    = (const float*)d_in[6];
    float* out = (float*)d_out;

    const int nN = in_sizes[2];                       // 100000
    const int nE = in_sizes[1] / 2;                   // 1600000
    const int nBk = (nN + BK_NODES - 1) >> BK_SHIFT;  // 391 buckets
    const int nGemm = (nN + 127) / 128;               // 782

    char* ws = (char*)d_ws;
    size_t woff = 0;
    auto take = [&](size_t bytes) {
        void* p = ws + woff;
        woff += (bytes + 15) & ~(size_t)15;
        return p;
    };
    unsigned char*  h_f8   = (unsigned char*)take((size_t)nN * F);
    unsigned short* agg_bf = (unsigned short*)take((size_t)nN * F * 2);
    int2*  tmp      = (int2*)take((size_t)nBk * BK_CAP * 8);
    int*   csr      = (int*)take((size_t)nBk * BK_CAP * 4);
    int*   cnt      = (int*)take((size_t)nN * 4);
    int*   off      = (int*)take((size_t)nN * 4);
    float* dinv     = (float*)take((size_t)nN * 4);
    int*   bcursor  = (int*)take((size_t)nBk * 4);

    hipMemsetAsync(bcursor, 0, (size_t)nBk * 4, stream);
    scatter_gemm_kernel<<<NSCAT + nGemm, 256, 65536, stream>>>(
        ei, nE, batch, nN, x, W1, h_f8, bcursor, tmp, nBk);
    bucket_build_kernel<<<nBk, 256, 0, stream>>>(tmp, bcursor, nN, off, cnt,
                                                 dinv, csr);
    aggregate_kernel<<<(nN + 31) / 32, 256, 0, stream>>>(h_f8, csr, off, cnt,
                                                         dinv, b1, agg_bf, nN);
    pool_final_kernel<<<N_GRAPHS, 256, 0, stream>>>(agg_bf, batch, nN, W2, b2, out);
}

// Round 10
// 122.650 us; speedup vs baseline: 1.5665x; 1.0623x over previous
//
#include <hip/hip_runtime.h>
#include <math.h>

#define F 128   // F_IN == F_HID == F_OUT == 128
#define N_GRAPHS 256
#define BK_SHIFT 8                // 256 nodes per bucket
#define BK_NODES 256
#define BK_CAP 6144               // padded per-bucket capacity (mean ~4092, +32 sigma)
#define MAXBK 512                 // LDS bucket-histogram capacity (nBk = 391)
#define SC_CAP 3200               // scatter LDS edge-chunk capacity
#define NSCAT 512                 // scatter blocks in fused kernel A

typedef __attribute__((ext_vector_type(4))) float f32x4;
typedef __attribute__((ext_vector_type(2))) float f32x2;
typedef __attribute__((ext_vector_type(8))) short bf16x8;
typedef __attribute__((ext_vector_type(8))) unsigned short u16x8;

// ---- bf16 helpers -----------------------------------------------------------
__device__ __forceinline__ unsigned short f2bf(float f) {
    unsigned u = __float_as_uint(f);
    unsigned r = (u + 0x7FFFu + ((u >> 16) & 1u)) >> 16;  // RNE
    return (unsigned short)r;
}
__device__ __forceinline__ float bf2f(unsigned short u) {
    return __uint_as_float(((unsigned)u) << 16);
}
// dtype-aware index read: int64 inputs have zero high words (values < 2^31)
__device__ __forceinline__ int idxval(const int* raw, int i, bool is32) {
    return is32 ? raw[i] : (int)((const long long*)raw)[i];
}

// ---- fp8 e4m3 helpers (hw converts w/ software fallback; self-consistent) ----
#if defined(__has_builtin)
#if __has_builtin(__builtin_amdgcn_cvt_pk_f32_fp8) && __has_builtin(__builtin_amdgcn_cvt_pk_fp8_f32)
#define HW_FP8 1
#endif
#endif

__device__ __forceinline__ unsigned char f2fp8(float f) {
#ifdef HW_FP8
    int p = __builtin_amdgcn_cvt_pk_fp8_f32(f, f, 0, false);
    return (unsigned char)(p & 0xFF);
#else
    float a = fabsf(f);
    unsigned s = (f < 0.f) ? 0x80u : 0u;
    if (a >= 448.f) return s | 0x7E;
    if (a < 0.015625f) {
        int m = (int)(a * 512.f + 0.5f);
        return s | (unsigned)m;
    }
    int ex;
    float fr = frexpf(a, &ex);
    int e = ex - 1;
    int q = (int)(a * exp2f((float)(3 - e)) + 0.5f) - 8;
    if (q == 8) { q = 0; e += 1; }
    return s | ((unsigned)(e + 7) << 3) | (unsigned)q;
#endif
}

// 16 fp8 (uint4) fused multiply-add into acc[16] with scalar weight w
__device__ __forceinline__ void fp8x16_fma(uint4 v, float w, float* acc) {
#ifdef HW_FP8
    f32x2 p;
    p = __builtin_amdgcn_cvt_pk_f32_fp8((int)v.x, false); acc[0]  += w * p[0]; acc[1]  += w * p[1];
    p = __builtin_amdgcn_cvt_pk_f32_fp8((int)v.x, true);  acc[2]  += w * p[0]; acc[3]  += w * p[1];
    p = __builtin_amdgcn_cvt_pk_f32_fp8((int)v.y, false); acc[4]  += w * p[0]; acc[5]  += w * p[1];
    p = __builtin_amdgcn_cvt_pk_f32_fp8((int)v.y, true);  acc[6]  += w * p[0]; acc[7]  += w * p[1];
    p = __builtin_amdgcn_cvt_pk_f32_fp8((int)v.z, false); acc[8]  += w * p[0]; acc[9]  += w * p[1];
    p = __builtin_amdgcn_cvt_pk_f32_fp8((int)v.z, true);  acc[10] += w * p[0]; acc[11] += w * p[1];
    p = __builtin_amdgcn_cvt_pk_f32_fp8((int)v.w, false); acc[12] += w * p[0]; acc[13] += w * p[1];
    p = __builtin_amdgcn_cvt_pk_f32_fp8((int)v.w, true);  acc[14] += w * p[0]; acc[15] += w * p[1];
#else
    unsigned ww[4] = {v.x, v.y, v.z, v.w};
#pragma unroll
    for (int j = 0; j < 16; ++j) {
        unsigned b = (ww[j >> 2] >> ((j & 3) * 8)) & 0xFF;
        int e = (b >> 3) & 0xF, m = b & 7;
        float val = e ? ldexpf((float)(8 + m), e - 10) : ldexpf((float)m, -9);
        acc[j] += (b & 0x80) ? -(w * val) : (w * val);
    }
#endif
}

// ---------------------------------------------------------------------------
// K0: W1 (f32 [k][n]) -> W1T (bf16 [n][k]). 16K elems, one-shot, ~2us.
// ---------------------------------------------------------------------------
__global__ __launch_bounds__(256) void w1t_kernel(
    const float* __restrict__ W1, unsigned short* __restrict__ W1T) {
    int i = blockIdx.x * 256 + threadIdx.x;   // 16384
    int k = i >> 7, n = i & 127;
    W1T[n * F + k] = f2bf(W1[i]);
}

// ---------------------------------------------------------------------------
// Kernel A: FUSED scatter || gemm (independent work, 32KB dynamic LDS aliased
// -> 5 blocks/CU).
// Blocks [0,NSCAT): reservation bucket-scatter of raw edges into PACKED tmp
//   (r | local_c<<20; local_c = c&255 recoverable since bucket is positional).
// Blocks [NSCAT,..): h = x @ W1 MFMA tiles, UNSCALED fp8 out; B-frags read
//   straight from L2-resident W1T.
// ---------------------------------------------------------------------------
__global__ __launch_bounds__(256) void scatter_gemm_kernel(
    const int* __restrict__ ei_raw, int nE,
    const int* __restrict__ batch_raw, int nN,
    const float* __restrict__ x, const unsigned short* __restrict__ W1T,
    unsigned char* __restrict__ h_f8,
    int* __restrict__ bcursor, int* __restrict__ tmp, int nBk) {
    extern __shared__ char smem[];
    int t = threadIdx.x;

    if (blockIdx.x < NSCAT) {
        // ---------------- scatter path (29.6KB LDS) ----------------
        int2* ebuf  = (int2*)smem;                       // SC_CAP*8 = 25.6KB
        int*  hist  = (int*)(smem + SC_CAP * 8);         // 2KB
        int*  rbase = hist + MAXBK;                      // 2KB
        bool is32 = (batch_raw[nN - 1] != 0);
        int cs = (nE + NSCAT - 1) / NSCAT;               // 3125 <= SC_CAP
        int e0 = blockIdx.x * cs;
        int e1 = min(nE, e0 + cs);

        for (int s0 = e0; s0 < e1; s0 += SC_CAP) {
            int m = min(SC_CAP, e1 - s0);
            for (int i = t; i < nBk; i += 256) hist[i] = 0;
            __syncthreads();
            for (int i = t; i < m; i += 256) {
                int r = idxval(ei_raw, s0 + i, is32);
                int c = idxval(ei_raw, nE + s0 + i, is32);
                ebuf[i] = make_int2(r, c);
                atomicAdd(&hist[c >> BK_SHIFT], 1);
            }
            __syncthreads();
            for (int i = t; i < nBk; i += 256) {
                int hv = hist[i];
                rbase[i] = hv ? (i * BK_CAP + atomicAdd(&bcursor[i], hv)) : 0;
                hist[i] = 0;
            }
            __syncthreads();
            for (int i = t; i < m; i += 256) {
                int2 e = ebuf[i];
                int b = e.y >> BK_SHIFT;
                int pos = rbase[b] + atomicAdd(&hist[b], 1);
                if (pos < (b + 1) * BK_CAP)  // capacity guard
                    tmp[pos] = e.x | ((e.y & (BK_NODES - 1)) << 20);
            }
            __syncthreads();
        }
    } else {
        // ---------------- gemm path (32KB LDS) ----------------
        unsigned short* xs = (unsigned short*)smem;      // 128*128 bf16 swizzled
        int row0 = (blockIdx.x - NSCAT) * 128;

#pragma unroll
        for (int j = 0; j < 16; ++j) {
            int idx = t + j * 256;        // float4 index within [128][32]
            int r = idx >> 5, c4 = idx & 31;
            int gr = row0 + r;
            float4 v = make_float4(0.f, 0.f, 0.f, 0.f);
            if (gr < nN) v = ((const float4*)x)[(size_t)gr * 32 + c4];
            ushort4 o;
            o.x = f2bf(v.x); o.y = f2bf(v.y); o.z = f2bf(v.z); o.w = f2bf(v.w);
            int byte = (r * 256 + c4 * 8) ^ ((r & 7) << 4);
            *(ushort4*)((char*)xs + byte) = o;
        }
        __syncthreads();

        int lane = t & 63;
        int w = t >> 6;              // wave 0..3
        int m0 = (w >> 1) * 64;
        int n0 = (w & 1) * 64;
        int l15 = lane & 15;
        int lg = lane >> 4;

        f32x4 acc[4][4] = {};
#pragma unroll
        for (int ks = 0; ks < 4; ++ks) {
            bf16x8 a[4], b[4];
#pragma unroll
            for (int i = 0; i < 4; ++i) {
                int r = m0 + i * 16 + l15;
                int byte = (r * 256 + ks * 64 + lg * 16) ^ ((r & 7) << 4);
                a[i] = *(const bf16x8*)((const char*)xs + byte);
            }
#pragma unroll
            for (int j = 0; j < 4; ++j) {
                int n = n0 + j * 16 + l15;
                b[j] = *(const bf16x8*)(W1T + (size_t)n * F + ks * 32 + lg * 8);
            }
#pragma unroll
            for (int i = 0; i < 4; ++i)
#pragma unroll
                for (int j = 0; j < 4; ++j)
                    acc[i][j] = __builtin_amdgcn_mfma_f32_16x16x32_bf16(
                        a[i], b[j], acc[i][j], 0, 0, 0);
        }

        // epilogue: store UNSCALED fp8
#pragma unroll
        for (int i = 0; i < 4; ++i) {
#pragma unroll
            for (int r = 0; r < 4; ++r) {
                int gm = row0 + m0 + i * 16 + lg * 4 + r;
                if (gm < nN) {
#pragma unroll
                    for (int j = 0; j < 4; ++j) {
                        int n = n0 + j * 16 + l15;
                        h_f8[(size_t)gm * F + n] = f2fp8(acc[i][j][r]);
                    }
                }
            }
        }
    }
}

// ---------------------------------------------------------------------------
// Kernel B: per-bucket build (single global pass; packed tmp staged in 24KB
// LDS): cnt, dinv, 4-aligned absolute offsets, src-only CSR. Atomics LDS-local.
// ---------------------------------------------------------------------------
__global__ __launch_bounds__(256) void bucket_build_kernel(
    const int* __restrict__ tmp, const int* __restrict__ bfill, int nN,
    int* __restrict__ off, int* __restrict__ cnt, float* __restrict__ dinv,
    int* __restrict__ csr) {
    __shared__ int ebuf[BK_CAP];      // 24KB
    __shared__ int h[BK_NODES];
    __shared__ int pfx[BK_NODES];
    __shared__ int lcur[BK_NODES];
    int b = blockIdx.x;
    int t = threadIdx.x;
    int nodeLo = b << BK_SHIFT;
    int base = b * BK_CAP;
    int m = min(bfill[b], BK_CAP);

    h[t] = 0;
    for (int i = t; i < m; i += 256) ebuf[i] = tmp[base + i];
    __syncthreads();
    for (int i = t; i < m; i += 256)
        atomicAdd(&h[ebuf[i] >> 20], 1);
    __syncthreads();
    int own = h[t];
    int pad = (own + 3) & ~3;       // 4-align each node's list
    pfx[t] = pad;
    __syncthreads();
    for (int st = 1; st < 256; st <<= 1) {
        int add = (t >= st) ? pfx[t - st] : 0;
        __syncthreads();
        pfx[t] += add;
        __syncthreads();
    }
    int myoff = base + pfx[t] - pad;
    lcur[t] = myoff;
    int node = nodeLo + t;
    if (node < nN) {
        off[node] = myoff;
        cnt[node] = own;
        dinv[node] = rsqrtf((float)(own + 1));  // +1 self-loop
    }
    __syncthreads();
    for (int i = t; i < m; i += 256) {
        int e = ebuf[i];
        int pos = atomicAdd(&lcur[e >> 20], 1);
        csr[pos] = e & 0xFFFFF;
    }
}

// ---------------------------------------------------------------------------
// Kernel C: gather-aggregate, fp8 rows, per-src dinv gather:
//   agg[c] = relu(b1 + dinv[c] * (dinv[c]*h[c] + sum_e dinv[src]*h[src]))
// 8 lanes x uint4 (16 fp8) per row, 32 nodes / 256-thr block.
// ---------------------------------------------------------------------------
__global__ __launch_bounds__(256) void aggregate_kernel(
    const unsigned char* __restrict__ h_f8, const int* __restrict__ csr,
    const int* __restrict__ off, const int* __restrict__ cnt,
    const float* __restrict__ dinv, const float* __restrict__ b1,
    unsigned short* __restrict__ agg_bf, int nN) {
    int t = threadIdx.x;
    int lane = t & 7;                  // features lane*16 .. lane*16+15
    int c = blockIdx.x * 32 + (t >> 3);
    if (c >= nN) return;

    const uint4* h4 = (const uint4*)h_f8;   // 8 x 16B per row
    int n = cnt[c];
    float dc = rsqrtf((float)(n + 1));
    float acc[16];
#pragma unroll
    for (int j = 0; j < 16; ++j) acc[j] = 0.f;
    fp8x16_fma(h4[(size_t)c * 8 + lane], dc, acc);   // self term (dinv[c]*h[c])

    int lo = off[c];                   // 4-aligned
    int k = 0;
    for (; k + 4 <= n; k += 4) {
        int4 e = *(const int4*)(csr + lo + k);
        float w0 = dinv[e.x];
        float w1 = dinv[e.y];
        float w2 = dinv[e.z];
        float w3 = dinv[e.w];
        uint4 v0 = h4[(size_t)e.x * 8 + lane];
        uint4 v1 = h4[(size_t)e.y * 8 + lane];
        uint4 v2 = h4[(size_t)e.z * 8 + lane];
        uint4 v3 = h4[(size_t)e.w * 8 + lane];
        fp8x16_fma(v0, w0, acc);
        fp8x16_fma(v1, w1, acc);
        fp8x16_fma(v2, w2, acc);
        fp8x16_fma(v3, w3, acc);
    }
    if (k < n) {
        int4 e = *(const int4*)(csr + lo + k);   // aligned; pad slots guarded
        fp8x16_fma(h4[(size_t)e.x * 8 + lane], dinv[e.x], acc);
        if (k + 1 < n) fp8x16_fma(h4[(size_t)e.y * 8 + lane], dinv[e.y], acc);
        if (k + 2 < n) fp8x16_fma(h4[(size_t)e.z * 8 + lane], dinv[e.z], acc);
    }

    const float* b1p = b1 + lane * 16;
    u16x8 r0, r1;
#pragma unroll
    for (int j = 0; j < 8; ++j) {
        r0[j] = f2bf(fmaxf(b1p[j] + dc * acc[j], 0.f));
        r1[j] = f2bf(fmaxf(b1p[8 + j] + dc * acc[8 + j], 0.f));
    }
    *(u16x8*)(agg_bf + (size_t)c * F + lane * 16) = r0;
    *(u16x8*)(agg_bf + (size_t)c * F + lane * 16 + 8) = r1;
}

// ---------------------------------------------------------------------------
// Kernel D: fused global-mean-pool + linear + tanh. One block per graph.
// ---------------------------------------------------------------------------
__global__ __launch_bounds__(256) void pool_final_kernel(
    const unsigned short* __restrict__ agg_bf,
    const int* __restrict__ batch_raw, int nN,
    const float* __restrict__ W2, const float* __restrict__ b2,
    float* __restrict__ out) {
    int g = blockIdx.x;
    bool is32 = (batch_raw[nN - 1] != 0);
    __shared__ int bounds[2];
    __shared__ float sd[16][F];
    __shared__ float ps[F];
    int t = threadIdx.x;
    if (t < 2) {
        int target = g + t;
        int lo = 0, hi = nN;
        while (lo < hi) {
            int mid = (lo + hi) >> 1;
            if (idxval(batch_raw, mid, is32) < target) lo = mid + 1; else hi = mid;
        }
        bounds[t] = lo;
    }
    __syncthreads();
    int lo = bounds[0], hi = bounds[1];

    int lane = t & 15;
    int grp = t >> 4;
    const u16x8* a8 = (const u16x8*)agg_bf;
    float acc[8];
#pragma unroll
    for (int j = 0; j < 8; ++j) acc[j] = 0.f;
    for (int n = lo + grp; n < hi; n += 16) {
        u16x8 v = a8[(size_t)n * 16 + lane];
#pragma unroll
        for (int j = 0; j < 8; ++j) acc[j] += bf2f(v[j]);
    }
#pragma unroll
    for (int j = 0; j < 8; ++j) sd[grp][lane * 8 + j] = acc[j];
    __syncthreads();

    if (t < F) {
        float s = 0.f;
#pragma unroll
        for (int i = 0; i < 16; ++i) s += sd[i][t];
        float cntf = (float)(hi - lo);
        ps[t] = s / fmaxf(cntf, 1.0f);
    }
    __syncthreads();

    if (t < F) {
        float s = b2[t];
        for (int k = 0; k < F; ++k) s += ps[k] * W2[k * F + t];
        out[g * F + t] = tanhf(s);
    }
}

// ---------------------------------------------------------------------------
extern "C" void kernel_launch(void* const* d_in, const int* in_sizes, int n_in,
                              void* d_out, int out_size, void* d_ws, size_t ws_size,
                              hipStream_t stream) {
    const float* x     = (const float*)d_in[0];
    const int*   ei    = (const int*)d_in[1];
    const int*   batch = (const int*)d_in[2];
    const float* W1    = (const float*)d_in[3];
    const float* b1    = (const float*)d_in[4];
    const float* W2    = (const float*)d_in[5];
    const float* b2    = (const float*)d_in[6];
    float* out = (float*)d_out;

    const int nN = in_sizes[2];                       // 100000
    const int nE = in_sizes[1] / 2;                   // 1600000
    const int nBk = (nN + BK_NODES - 1) >> BK_SHIFT;  // 391 buckets
    const int nGemm = (nN + 127) / 128;               // 782

    char* ws = (char*)d_ws;
    size_t woff = 0;
    auto take = [&](size_t bytes) {
        void* p = ws + woff;
        woff += (bytes + 15) & ~(size_t)15;
        return p;
    };
    unsigned char*  h_f8   = (unsigned char*)take((size_t)nN * F);
    unsigned short* agg_bf = (unsigned short*)take((size_t)nN * F * 2);
    int*   tmp      = (int*)take((size_t)nBk * BK_CAP * 4);
    int*   csr      = (int*)take((size_t)nBk * BK_CAP * 4);
    int*   cnt      = (int*)take((size_t)nN * 4);
    int*   off      = (int*)take((size_t)nN * 4);
    float* dinv     = (float*)take((size_t)nN * 4);
    unsigned short* W1T = (unsigned short*)take((size_t)F * F * 2);
    int*   bcursor  = (int*)take((size_t)nBk * 4);

    hipMemsetAsync(bcursor, 0, (size_t)nBk * 4, stream);
    w1t_kernel<<<F * F / 256, 256, 0, stream>>>(W1, W1T);
    scatter_gemm_kernel<<<NSCAT + nGemm, 256, 32768, stream>>>(
        ei, nE, batch, nN, x, W1T, h_f8, bcursor, tmp, nBk);
    bucket_build_kernel<<<nBk, 256, 0, stream>>>(tmp, bcursor, nN, off, cnt,
                                                 dinv, csr);
    aggregate_kernel<<<(nN + 31) / 32, 256, 0, stream>>>(h_f8, csr, off, cnt,
                                                         dinv, b1, agg_bf, nN);
    pool_final_kernel<<<N_GRAPHS, 256, 0, stream>>>(agg_bf, batch, nN, W2, b2, out);
}